// Round 1
// baseline (312.877 us; speedup 1.0000x reference)
//
#include <hip/hip_runtime.h>

// Problem constants (from reference): x [32,64,64,64] f32, embed [64,512] f32.
#define N_VEC 131072   // 32*64*64 vectors
#define D 64           // embedding dim
#define K 512          // number of codes
#define VPW 8          // vectors per wave in argmin kernel
#define NB_GATHER 2048 // blocks for gather/diff kernel

// ---------------------------------------------------------------------------
// Kernel A: nearest-code search.  lane = code (within a group of 64 codes),
// 8 groups cover K=512.  Each wave handles VPW vectors; x is read at a
// wave-uniform address (readfirstlane base) so loads broadcast / scalarize.
// Writes emd_id as float into the id region of d_out.
// ---------------------------------------------------------------------------
__global__ __launch_bounds__(256) void vq_argmin_kernel(
    const float* __restrict__ x, const float* __restrict__ embed,
    float* __restrict__ idf)
{
  const int lane = threadIdx.x & 63;
  const int wave = (blockIdx.x << 2) + (threadIdx.x >> 6);
  const int vbase = __builtin_amdgcn_readfirstlane(wave * VPW);

  float best[VPW];
  int bidx[VPW];
#pragma unroll
  for (int i = 0; i < VPW; ++i) { best[i] = 3.4e38f; bidx[i] = 0; }

  const float4* xq = reinterpret_cast<const float4*>(x) + (size_t)vbase * (D / 4);

#pragma unroll 1   // keep g-loop rolled: body ~800 instr fits I-cache
  for (int g = 0; g < K / 64; ++g) {
    const int k = (g << 6) + lane;
    // Load this lane's codebook column + its squared norm.
    float ecol[D];
    float nrm = 0.f;
#pragma unroll
    for (int d = 0; d < D; ++d) {
      ecol[d] = embed[d * K + k];
      nrm = fmaf(ecol[d], ecol[d], nrm);
    }
    // Score every vector of this wave's chunk against these 64 codes.
#pragma unroll
    for (int i = 0; i < VPW; ++i) {
      float dot = 0.f;
#pragma unroll
      for (int dq = 0; dq < D / 4; ++dq) {
        float4 xv = xq[i * (D / 4) + dq];
        dot = fmaf(xv.x, ecol[4 * dq + 0], dot);
        dot = fmaf(xv.y, ecol[4 * dq + 1], dot);
        dot = fmaf(xv.z, ecol[4 * dq + 2], dot);
        dot = fmaf(xv.w, ecol[4 * dq + 3], dot);
      }
      // dist = ||x||^2 - 2 x.e + ||e||^2 ; drop the row-constant ||x||^2.
      const float score = fmaf(-2.f, dot, nrm);
      if (score < best[i]) { best[i] = score; bidx[i] = k; }  // strict <: first-min
    }
  }

  // Cross-lane reduce per vector: (min score, tie -> min index) == np.argmax(-dist).
#pragma unroll
  for (int i = 0; i < VPW; ++i) {
    float s = best[i];
    int b = bidx[i];
#pragma unroll
    for (int off = 32; off > 0; off >>= 1) {
      const float s2 = __shfl_down(s, off, 64);
      const int b2 = __shfl_down(b, off, 64);
      if (s2 < s || (s2 == s && b2 < b)) { s = s2; b = b2; }
    }
    if (lane == 0) idf[vbase + i] = (float)b;
  }
}

// ---------------------------------------------------------------------------
// Kernel B: gather q = embed.T[id], write q_st (== q numerically), and
// accumulate per-block partial sums of (q - x)^2 into d_ws (deterministic).
// ---------------------------------------------------------------------------
__global__ __launch_bounds__(256) void vq_gather_kernel(
    const float* __restrict__ x, const float* __restrict__ embed,
    const float* __restrict__ idf, float* __restrict__ q,
    float* __restrict__ partial)
{
  const int tid = blockIdx.x * 256 + threadIdx.x;
  const int stride = gridDim.x * 256;
  float acc = 0.f;
  for (int idx = tid; idx < N_VEC * (D / 4); idx += stride) {
    const int v = idx >> 4;
    const int d0 = (idx & 15) << 2;
    const int id = (int)idf[v];            // float ids are exact ints < 512
    const float4 xv = reinterpret_cast<const float4*>(x)[idx];
    const float q0 = embed[(d0 + 0) * K + id];
    const float q1 = embed[(d0 + 1) * K + id];
    const float q2 = embed[(d0 + 2) * K + id];
    const float q3 = embed[(d0 + 3) * K + id];
    const float e0 = q0 - xv.x, e1 = q1 - xv.y, e2 = q2 - xv.z, e3 = q3 - xv.w;
    acc += (e0 * e0 + e1 * e1) + (e2 * e2 + e3 * e3);
    float4 qv;
    qv.x = q0; qv.y = q1; qv.z = q2; qv.w = q3;
    reinterpret_cast<float4*>(q)[idx] = qv;
  }
  // Deterministic block reduction: wave shuffle tree then LDS.
  acc += __shfl_down(acc, 32, 64);
  acc += __shfl_down(acc, 16, 64);
  acc += __shfl_down(acc, 8, 64);
  acc += __shfl_down(acc, 4, 64);
  acc += __shfl_down(acc, 2, 64);
  acc += __shfl_down(acc, 1, 64);
  __shared__ float sred[4];
  if ((threadIdx.x & 63) == 0) sred[threadIdx.x >> 6] = acc;
  __syncthreads();
  if (threadIdx.x == 0)
    partial[blockIdx.x] = (sred[0] + sred[1]) + (sred[2] + sred[3]);
}

// ---------------------------------------------------------------------------
// Kernel C: sum the NB_GATHER partials (fixed order) -> mean -> d_out scalar.
// ---------------------------------------------------------------------------
__global__ __launch_bounds__(256) void vq_finalize_kernel(
    const float* __restrict__ partial, float* __restrict__ out)
{
  float acc = 0.f;
  for (int i = threadIdx.x; i < NB_GATHER; i += 256) acc += partial[i];
  acc += __shfl_down(acc, 32, 64);
  acc += __shfl_down(acc, 16, 64);
  acc += __shfl_down(acc, 8, 64);
  acc += __shfl_down(acc, 4, 64);
  acc += __shfl_down(acc, 2, 64);
  acc += __shfl_down(acc, 1, 64);
  __shared__ float sred[4];
  if ((threadIdx.x & 63) == 0) sred[threadIdx.x >> 6] = acc;
  __syncthreads();
  if (threadIdx.x == 0)
    out[0] = ((sred[0] + sred[1]) + (sred[2] + sred[3])) * (1.0f / (float)(N_VEC * D));
}

extern "C" void kernel_launch(void* const* d_in, const int* in_sizes, int n_in,
                              void* d_out, int out_size, void* d_ws, size_t ws_size,
                              hipStream_t stream) {
  const float* x = (const float*)d_in[0];
  const float* embed = (const float*)d_in[1];
  float* out = (float*)d_out;
  float* q = out;                  // [0, 8388608): q_st
  float* diff = out + 8388608;     // [8388608]: commitment loss scalar
  float* idf = out + 8388609;      // [8388609, +131072): emd_id as float
  float* partial = (float*)d_ws;   // NB_GATHER floats of scratch

  vq_argmin_kernel<<<N_VEC / (4 * VPW), 256, 0, stream>>>(x, embed, idf);
  vq_gather_kernel<<<NB_GATHER, 256, 0, stream>>>(x, embed, idf, q, partial);
  vq_finalize_kernel<<<1, 256, 0, stream>>>(partial, diff);
}

// Round 2
// 174.495 us; speedup vs baseline: 1.7930x; 1.7930x over previous
//
#include <hip/hip_runtime.h>

// Problem constants: x [32,64,64,64] f32, embed [64,512] f32.
#define N_VEC 131072   // 32*64*64 vectors
#define D 64           // embedding dim
#define K 512          // number of codes
#define QT 64          // queries per block
#define NB_GATHER 2048 // blocks for gather/diff kernel

// ---------------------------------------------------------------------------
// Kernel 0: per-code squared norms -> d_ws[0..511]. Same fp32 fma order as the
// round-1 kernel (d ascending) so downstream numerics are bit-identical.
// ---------------------------------------------------------------------------
__global__ __launch_bounds__(512) void vq_norm_kernel(
    const float* __restrict__ embed, float* __restrict__ nrm)
{
  const int k = threadIdx.x;  // 512 threads, 1 block
  float s = 0.f;
#pragma unroll
  for (int d = 0; d < D; ++d) { const float e = embed[d * K + k]; s = fmaf(e, e, s); }
  nrm[k] = s;
}

// ---------------------------------------------------------------------------
// Kernel A: nearest-code search. Block = 512 threads (8 waves), one 64-query
// tile per block. Codebook processed in 4 groups of 128 codes staged in LDS
// as [d][128] (conflict-free b32: lanes consecutive). Query tile in LDS as
// [q][64], read as b128 broadcast. Per lane: 2 codes (lane, lane+64 of the
// group) x 8 queries of its wave -> 16 fp32 accumulators, zero spill.
// ---------------------------------------------------------------------------
__global__ __launch_bounds__(512) void vq_argmin_kernel(
    const float* __restrict__ x, const float* __restrict__ embed,
    const float* __restrict__ nrm, float* __restrict__ idf)
{
  __shared__ float e_lds[D * 128];   // 32 KB: current code-group tile [d][c]
  __shared__ float x_lds[QT * D];    // 16 KB: query tile [q][d]
  const int tid  = threadIdx.x;
  const int lane = tid & 63;
  const int wv   = tid >> 6;         // 0..7
  const int qbase = blockIdx.x * QT;

  // Stage x tile (16 KB, layouts identical in global and LDS -> linear copy).
  {
    const float4* src = reinterpret_cast<const float4*>(x + (size_t)qbase * D);
#pragma unroll
    for (int j = 0; j < 2; ++j) {
      const int f4 = tid + j * 512;
      reinterpret_cast<float4*>(x_lds)[f4] = src[f4];
    }
  }

  float best[8], acc0[8], acc1[8];
  int bidx[8];
#pragma unroll
  for (int i = 0; i < 8; ++i) { best[i] = 3.4e38f; bidx[i] = 0; }

#pragma unroll 1   // keep group loop rolled: body ~1.4K instr fits I-cache
  for (int g = 0; g < 4; ++g) {
    // Prefetch this group's code norms (L2-hot, consumed ~1k cycles later).
    const float nr0 = nrm[g * 128 + lane];
    const float nr1 = nrm[g * 128 + 64 + lane];

    __syncthreads();   // previous group's compute done before overwrite
#pragma unroll
    for (int j = 0; j < 4; ++j) {       // stage e tile: 8192 floats / 512 thr
      const int f4 = tid + j * 512;
      const int d = f4 >> 5;            // 32 float4 per 128-code row
      const int c = (f4 & 31) << 2;
      *reinterpret_cast<float4*>(&e_lds[d * 128 + c]) =
          *reinterpret_cast<const float4*>(&embed[d * K + g * 128 + c]);
    }
    __syncthreads();   // e (and, at g=0, x) visible to all waves

#pragma unroll
    for (int i = 0; i < 8; ++i) { acc0[i] = 0.f; acc1[i] = 0.f; }

#pragma unroll
    for (int ch = 0; ch < 16; ++ch) {   // 4 dims per chunk
      const int d0 = ch * 4;
      const float e00 = e_lds[(d0 + 0) * 128 + lane];
      const float e01 = e_lds[(d0 + 0) * 128 + 64 + lane];
      const float e10 = e_lds[(d0 + 1) * 128 + lane];
      const float e11 = e_lds[(d0 + 1) * 128 + 64 + lane];
      const float e20 = e_lds[(d0 + 2) * 128 + lane];
      const float e21 = e_lds[(d0 + 2) * 128 + 64 + lane];
      const float e30 = e_lds[(d0 + 3) * 128 + lane];
      const float e31 = e_lds[(d0 + 3) * 128 + 64 + lane];
#pragma unroll
      for (int i = 0; i < 8; ++i) {
        const float4 xv =
            *reinterpret_cast<const float4*>(&x_lds[(wv * 8 + i) * D + d0]);
        acc0[i] = fmaf(xv.x, e00, acc0[i]);
        acc0[i] = fmaf(xv.y, e10, acc0[i]);
        acc0[i] = fmaf(xv.z, e20, acc0[i]);
        acc0[i] = fmaf(xv.w, e30, acc0[i]);
        acc1[i] = fmaf(xv.x, e01, acc1[i]);
        acc1[i] = fmaf(xv.y, e11, acc1[i]);
        acc1[i] = fmaf(xv.z, e21, acc1[i]);
        acc1[i] = fmaf(xv.w, e31, acc1[i]);
      }
    }

    // score = ||e||^2 - 2 x.e (row-constant ||x||^2 dropped); strict < keeps
    // the first (lowest-index) minimum; per-lane visit order is ascending k.
    const int k0 = g * 128 + lane;
#pragma unroll
    for (int i = 0; i < 8; ++i) {
      const float s0 = fmaf(-2.f, acc0[i], nr0);
      if (s0 < best[i]) { best[i] = s0; bidx[i] = k0; }
      const float s1 = fmaf(-2.f, acc1[i], nr1);
      if (s1 < best[i]) { best[i] = s1; bidx[i] = k0 + 64; }
    }
  }

  // Cross-lane argmin per query: (min score, tie -> min index) == np semantics.
#pragma unroll
  for (int i = 0; i < 8; ++i) {
    float s = best[i];
    int b = bidx[i];
#pragma unroll
    for (int off = 32; off > 0; off >>= 1) {
      const float s2 = __shfl_down(s, off, 64);
      const int   b2 = __shfl_down(b, off, 64);
      if (s2 < s || (s2 == s && b2 < b)) { s = s2; b = b2; }
    }
    if (lane == 0) idf[qbase + wv * 8 + i] = (float)b;
  }
}

// ---------------------------------------------------------------------------
// Kernel B: gather q = embed.T[id], write q_st (== q numerically), and
// accumulate per-block partial sums of (q - x)^2 into d_ws (deterministic).
// ---------------------------------------------------------------------------
__global__ __launch_bounds__(256) void vq_gather_kernel(
    const float* __restrict__ x, const float* __restrict__ embed,
    const float* __restrict__ idf, float* __restrict__ q,
    float* __restrict__ partial)
{
  const int tid = blockIdx.x * 256 + threadIdx.x;
  const int stride = gridDim.x * 256;
  float acc = 0.f;
  for (int idx = tid; idx < N_VEC * (D / 4); idx += stride) {
    const int v = idx >> 4;
    const int d0 = (idx & 15) << 2;
    const int id = (int)idf[v];            // float ids are exact ints < 512
    const float4 xv = reinterpret_cast<const float4*>(x)[idx];
    const float q0 = embed[(d0 + 0) * K + id];
    const float q1 = embed[(d0 + 1) * K + id];
    const float q2 = embed[(d0 + 2) * K + id];
    const float q3 = embed[(d0 + 3) * K + id];
    const float e0 = q0 - xv.x, e1 = q1 - xv.y, e2 = q2 - xv.z, e3 = q3 - xv.w;
    acc += (e0 * e0 + e1 * e1) + (e2 * e2 + e3 * e3);
    float4 qv;
    qv.x = q0; qv.y = q1; qv.z = q2; qv.w = q3;
    reinterpret_cast<float4*>(q)[idx] = qv;
  }
  acc += __shfl_down(acc, 32, 64);
  acc += __shfl_down(acc, 16, 64);
  acc += __shfl_down(acc, 8, 64);
  acc += __shfl_down(acc, 4, 64);
  acc += __shfl_down(acc, 2, 64);
  acc += __shfl_down(acc, 1, 64);
  __shared__ float sred[4];
  if ((threadIdx.x & 63) == 0) sred[threadIdx.x >> 6] = acc;
  __syncthreads();
  if (threadIdx.x == 0)
    partial[blockIdx.x] = (sred[0] + sred[1]) + (sred[2] + sred[3]);
}

// ---------------------------------------------------------------------------
// Kernel C: sum the NB_GATHER partials (fixed order) -> mean -> d_out scalar.
// ---------------------------------------------------------------------------
__global__ __launch_bounds__(256) void vq_finalize_kernel(
    const float* __restrict__ partial, float* __restrict__ out)
{
  float acc = 0.f;
  for (int i = threadIdx.x; i < NB_GATHER; i += 256) acc += partial[i];
  acc += __shfl_down(acc, 32, 64);
  acc += __shfl_down(acc, 16, 64);
  acc += __shfl_down(acc, 8, 64);
  acc += __shfl_down(acc, 4, 64);
  acc += __shfl_down(acc, 2, 64);
  acc += __shfl_down(acc, 1, 64);
  __shared__ float sred[4];
  if ((threadIdx.x & 63) == 0) sred[threadIdx.x >> 6] = acc;
  __syncthreads();
  if (threadIdx.x == 0)
    out[0] = ((sred[0] + sred[1]) + (sred[2] + sred[3])) * (1.0f / (float)(N_VEC * D));
}

extern "C" void kernel_launch(void* const* d_in, const int* in_sizes, int n_in,
                              void* d_out, int out_size, void* d_ws, size_t ws_size,
                              hipStream_t stream) {
  const float* x = (const float*)d_in[0];
  const float* embed = (const float*)d_in[1];
  float* out = (float*)d_out;
  float* q = out;                    // [0, 8388608): q_st
  float* diff = out + 8388608;       // [8388608]: commitment loss scalar
  float* idf = out + 8388609;        // [8388609, +131072): emd_id as float
  float* nrm = (float*)d_ws;         // [0, 512): code norms
  float* partial = (float*)d_ws + 512;  // NB_GATHER partial sums

  vq_norm_kernel<<<1, 512, 0, stream>>>(embed, nrm);
  vq_argmin_kernel<<<N_VEC / QT, 512, 0, stream>>>(x, embed, nrm, idf);
  vq_gather_kernel<<<NB_GATHER, 256, 0, stream>>>(x, embed, idf, q, partial);
  vq_finalize_kernel<<<1, 256, 0, stream>>>(partial, diff);
}